// Round 18
// baseline (156.694 us; speedup 1.0000x reference)
//
#include <hip/hip_runtime.h>
#include <hip/hip_bf16.h>

typedef short short8 __attribute__((ext_vector_type(8)));
typedef short short4v __attribute__((ext_vector_type(4)));
typedef float f32x4 __attribute__((ext_vector_type(4)));
typedef __bf16 bf16x8 __attribute__((ext_vector_type(8)));

// ---- stage a ROWSx64 bf16 tile via global_load_lds, 16B-chunk XOR swizzle --
template <int ROWS>
__device__ __forceinline__ void stage2(const __hip_bfloat16* __restrict__ g,
                                       int ld, short* lds, int t) {
    const int w = t >> 6;
    const int lane = t & 63;
#pragma unroll
    for (int i = 0; i < ROWS / 64; ++i) {
        const int cb = i * 512 + w * 64;     // wave-uniform chunk base
        const int c = cb + lane;
        const int row = c >> 3;
        const int kc = (c & 7) ^ (row & 7);
        __builtin_amdgcn_global_load_lds((const void*)(g + (long)row * ld + kc * 8),
                                         (void*)(lds + cb * 8), 16, 0, 0);
    }
}

// ======== fused xw_sm: P = softmax(mask(tanh(X*W+b) * Ut^T)) ================
// Per block: 64 t-rows, FULL A=256 (so alpha never leaves LDS).
// Phase 1 (XW): BM=64 x BN=256 x BK=64, K=1024. A (X f32) reg-staged -> bf16
//   LDS dbuf (1 granule/thread); B (Wt bf16) fragment-direct from L2
//   (512KB, resident). 8 waves, wave tile 64x32, acc[4][2]=32 regs.
//   Counted vmcnt(2) (only A-loads cross barriers).
// Handoff: tanh+bias in-reg -> alphaT LDS in the granule-XOR layout the SM
//   A-frag reads expect: elem(row,col) at row*256 + ((col>>3)^(row&7))*8+(col&7).
// Phase 2 (SM): r12 score_softmax body verbatim (Ut frag-direct depth-2,
//   shfl softmax, masked, P bf16 out). acc2[4][4]=64 regs (acc dead by then).
__global__ __launch_bounds__(512, 4) void xw_sm_kernel(
    const float* __restrict__ Xf,           // [32768][1024]
    const __hip_bfloat16* __restrict__ Wt,  // [256][1024]
    const __hip_bfloat16* __restrict__ Ut,  // [512][256]
    const float* __restrict__ bias,         // [256]
    const int* __restrict__ sen,            // [64]
    __hip_bfloat16* __restrict__ P) {       // [32768][512]
    __shared__ __align__(16) short smA[2][4096];      // 8KB x2: X tile 64x64 bf16
    __shared__ __align__(16) short alphaT[64 * 256];  // 32KB: alpha granule layout
    __shared__ float red[2][64][9];

    const int by = blockIdx.x;              // [0,512): 64 t-rows each
    const int t = threadIdx.x;
    const int w = t >> 6, lane = t & 63;    // 8 waves
    const int fr = lane & 15, quad = lane >> 4;

    const float* Ab = Xf + (long)by * 64 * 1024;

    // A granule map: 64 rows x 8 chunks = 512 granules, 1/thread
    const int arow = t >> 3;
    const int akc = ((t & 7) ^ (arow & 7)) * 8;

    f32x4 acc[4][2] = {};   // XW acc: rows m*16+quad*4+j, cols w*32+n*16+fr
    float4 rA0, rA1;

#define FX_LOAD_A(KT)                                                           \
    {                                                                           \
        const float* src = Ab + (long)arow * 1024 + (KT) * 64 + akc;            \
        rA0 = *(const float4*)(src);                                            \
        rA1 = *(const float4*)(src + 4);                                        \
    }

#define FX_WRITE_A(BUF)                                                         \
    {                                                                           \
        __hip_bfloat16 tmp[8] __attribute__((aligned(16)));                     \
        tmp[0] = __float2bfloat16(rA0.x); tmp[1] = __float2bfloat16(rA0.y);     \
        tmp[2] = __float2bfloat16(rA0.z); tmp[3] = __float2bfloat16(rA0.w);     \
        tmp[4] = __float2bfloat16(rA1.x); tmp[5] = __float2bfloat16(rA1.y);     \
        tmp[6] = __float2bfloat16(rA1.z); tmp[7] = __float2bfloat16(rA1.w);     \
        *(short8*)(void*)&smA[BUF][t * 8] = *(short8*)(void*)tmp;               \
    }

    FX_LOAD_A(0)
    FX_WRITE_A(0)          // compiler auto-waits on rA(0)
    FX_LOAD_A(1)
    __builtin_amdgcn_sched_barrier(0);
    asm volatile("s_waitcnt vmcnt(2)" ::: "memory");   // nothing older than A(1)
    asm volatile("s_waitcnt lgkmcnt(0)" ::: "memory");
    __builtin_amdgcn_s_barrier();
    __builtin_amdgcn_sched_barrier(0);

#pragma unroll
    for (int k = 0; k < 16; ++k) {
        {   // B-frags for this step, direct from L2 (Wt rows = w*32+n*16+fr)
            bf16x8 bfv[2][2];
#pragma unroll
            for (int ks = 0; ks < 2; ++ks)
#pragma unroll
                for (int n = 0; n < 2; ++n)
                    bfv[ks][n] = *(const bf16x8*)(const void*)(
                        Wt + (long)(w * 32 + n * 16 + fr) * 1024 +
                        k * 64 + ks * 32 + quad * 8);
            const short* At = &smA[k & 1][0];
            __builtin_amdgcn_s_setprio(1);
#pragma unroll
            for (int ks = 0; ks < 2; ++ks) {
                bf16x8 af[4];
                const int kc = ks * 4 + quad;
#pragma unroll
                for (int m = 0; m < 4; ++m) {
                    const int row = m * 16 + fr;
                    const int chunk = row * 8 + (kc ^ (row & 7));
                    af[m] = *(const bf16x8*)(const void*)(At + chunk * 8);
                }
#pragma unroll
                for (int m = 0; m < 4; ++m)
#pragma unroll
                    for (int n = 0; n < 2; ++n)
                        acc[m][n] = __builtin_amdgcn_mfma_f32_16x16x32_bf16(
                            af[m], bfv[ks][n], acc[m][n], 0, 0, 0);
            }
            __builtin_amdgcn_s_setprio(0);
        }
        if (k + 1 < 16) FX_WRITE_A((k + 1) & 1)   // auto-waits on rA(k+1)
        if (k + 2 < 16) FX_LOAD_A(k + 2)
        __builtin_amdgcn_sched_barrier(0);
        if (k + 2 < 16) {
            asm volatile("s_waitcnt vmcnt(2)" ::: "memory");
        } else if (k + 1 < 16) {
            asm volatile("s_waitcnt vmcnt(0)" ::: "memory");
        }
        if (k + 1 < 16) {
            asm volatile("s_waitcnt lgkmcnt(0)" ::: "memory");
            __builtin_amdgcn_s_barrier();
            __builtin_amdgcn_sched_barrier(0);
        }
    }
#undef FX_LOAD_A
#undef FX_WRITE_A

    // ---- handoff: tanh(acc+bias) -> alphaT (granule-XOR layout) ----
    __syncthreads();   // all waves done with smA / in K-loop epilogue
#pragma unroll
    for (int m = 0; m < 4; ++m)
#pragma unroll
        for (int n = 0; n < 2; ++n) {
            const int col = w * 32 + n * 16 + fr;
            const float bv = bias[col];
#pragma unroll
            for (int j = 0; j < 4; ++j) {
                const int row = m * 16 + quad * 4 + j;
                const float v = tanhf(acc[m][n][j] + bv);
                const __hip_bfloat16 hv = __float2bfloat16(v);
                alphaT[row * 256 + (((col >> 3) ^ (row & 7)) * 8) + (col & 7)] =
                    *(const short*)&hv;
            }
        }
    __syncthreads();

    // ---- phase 2: scores + masked softmax (r12 SM body) ----
    const long row0 = (long)by * 64;
    f32x4 acc2[4][4] = {};
    bf16x8 bfvs[2][4];

#define SM_LOAD_B(KT, S)                                                        \
    _Pragma("unroll") for (int n = 0; n < 4; ++n)                               \
        bfvs[S][n] = *(const bf16x8*)(const void*)(                             \
            Ut + (w * 64 + n * 16 + fr) * 256 + (KT) * 32 + quad * 8);

    SM_LOAD_B(0, 0)
    SM_LOAD_B(1, 1)

#define SM_STEP(KT)                                                             \
    {                                                                           \
        bf16x8 af[4];                                                           \
        _Pragma("unroll") for (int m = 0; m < 4; ++m) {                         \
            const int row = m * 16 + fr;                                        \
            const int g = row * 32 + (((KT) * 4 + quad) ^ (row & 7));           \
            af[m] = *(const bf16x8*)(const void*)(alphaT + g * 8);              \
        }                                                                       \
        _Pragma("unroll") for (int m = 0; m < 4; ++m)                           \
            _Pragma("unroll") for (int n = 0; n < 4; ++n)                       \
                acc2[m][n] = __builtin_amdgcn_mfma_f32_16x16x32_bf16(           \
                    af[m], bfvs[(KT) & 1][n], acc2[m][n], 0, 0, 0);             \
        if ((KT) + 2 < 8) { SM_LOAD_B((KT) + 2, (KT) & 1) }                     \
    }

    SM_STEP(0) SM_STEP(1) SM_STEP(2) SM_STEP(3)
    SM_STEP(4) SM_STEP(5) SM_STEP(6) SM_STEP(7)
#undef SM_STEP
#undef SM_LOAD_B
    __syncthreads();

    const int L = sen[row0 >> 9];
    bool valid[4];
#pragma unroll
    for (int n = 0; n < 4; ++n) valid[n] = (w * 64 + n * 16 + fr) < L;

    float mx[4][4];
#pragma unroll
    for (int m = 0; m < 4; ++m)
#pragma unroll
        for (int j = 0; j < 4; ++j) {
            float v = -3.0e38f;
#pragma unroll
            for (int n = 0; n < 4; ++n)
                if (valid[n]) v = fmaxf(v, acc2[m][n][j]);
#pragma unroll
            for (int off = 8; off >= 1; off >>= 1) v = fmaxf(v, __shfl_xor(v, off, 64));
            mx[m][j] = v;
        }
    if (fr == 0) {
#pragma unroll
        for (int m = 0; m < 4; ++m)
#pragma unroll
            for (int j = 0; j < 4; ++j) red[0][m * 16 + quad * 4 + j][w] = mx[m][j];
    }
    __syncthreads();
    float rmax[4][4];
#pragma unroll
    for (int m = 0; m < 4; ++m)
#pragma unroll
        for (int j = 0; j < 4; ++j) {
            const int row = m * 16 + quad * 4 + j;
            float v = red[0][row][0];
#pragma unroll
            for (int ww = 1; ww < 8; ++ww) v = fmaxf(v, red[0][row][ww]);
            rmax[m][j] = v;
        }

    float sum[4][4];
#pragma unroll
    for (int m = 0; m < 4; ++m)
#pragma unroll
        for (int j = 0; j < 4; ++j) {
            float s = 0.f;
#pragma unroll
            for (int n = 0; n < 4; ++n) {
                float e = valid[n] ? __expf(acc2[m][n][j] - rmax[m][j]) : 0.f;
                acc2[m][n][j] = e;
                s += e;
            }
#pragma unroll
            for (int off = 8; off >= 1; off >>= 1) s += __shfl_xor(s, off, 64);
            sum[m][j] = s;
        }
    if (fr == 0) {
#pragma unroll
        for (int m = 0; m < 4; ++m)
#pragma unroll
            for (int j = 0; j < 4; ++j) red[1][m * 16 + quad * 4 + j][w] = sum[m][j];
    }
    __syncthreads();
#pragma unroll
    for (int m = 0; m < 4; ++m)
#pragma unroll
        for (int j = 0; j < 4; ++j) {
            const int row = m * 16 + quad * 4 + j;
            float s = 0.f;
#pragma unroll
            for (int ww = 0; ww < 8; ++ww) s += red[1][row][ww];
            const float inv = 1.f / s;
#pragma unroll
            for (int n = 0; n < 4; ++n)
                P[(row0 + row) * 512 + w * 64 + n * 16 + fr] =
                    __float2bfloat16(acc2[m][n][j] * inv);
        }
}

// -------- gemm_pv v10 + T5 setprio (r17, unchanged) -------------------------
__global__ __launch_bounds__(512, 4) void gemm_pv_kernel(
    const __hip_bfloat16* __restrict__ P,  // [B*512][512]
    const float* __restrict__ Xf,          // [B*512][1024]
    float* __restrict__ Z) {               // [B*512][1024]
    __shared__ __align__(16) short smA[3][8192];   // 16KB x3
    __shared__ __align__(16) short smB[2][5120];   // 10KB x2

    int bx, by, bz;
    {
        const int lin = blockIdx.x + 8 * (blockIdx.y + 2 * blockIdx.z);  // [0,1024)
        const int xcd = lin & 7;
        const int idx = lin >> 3;                 // [0,128)
        const int grp = xcd * 16 + (idx >> 3);    // [0,128) = (by,bz) group
        bx = idx & 7;
        by = grp & 1;
        bz = grp >> 1;
    }

    const int t = threadIdx.x;
    const int w = t >> 6, lane = t & 63;
    const int wm = w >> 1, wn = w & 1;   // 4 x 2 waves
    const int fr = lane & 15, quad = lane >> 4;

    const __hip_bfloat16* Ab = P + ((long)bz * 512 + by * 256) * 512;
    const float* Bb = Xf + (long)bz * 512 * 1024 + bx * 128;

    int acb[2], arow[2], akc[2];
#pragma unroll
    for (int i = 0; i < 2; ++i) {
        acb[i] = i * 512 + w * 64;           // wave-uniform
        const int s = acb[i] + lane;
        arow[i] = s >> 2;
        akc[i] = ((s & 3) ^ ((arow[i] >> 1) & 3)) * 8;
    }
    const int bi = t & 15;
    const int bhc = t >> 4;   // 0..31

    f32x4 acc[4][4] = {};
    float4 r0, r1;

#define PV_ISSUE_A(KT, BUF)                                                     \
    _Pragma("unroll") for (int i = 0; i < 2; ++i)                               \
        __builtin_amdgcn_global_load_lds(                                       \
            (const void*)(Ab + (long)arow[i] * 512 + (KT) * 32 + akc[i]),       \
            (void*)(&smA[BUF][acb[i] * 8]), 16, 0, 0);

#define PV_LOAD_B(KT)                                                           \
    {                                                                           \
        const float* s0 = Bb + (long)((KT) * 32 + 2 * bi) * 1024 + bhc * 4;     \
        r0 = *(const float4*)(s0);                                              \
        r1 = *(const float4*)(s0 + 1024);                                       \
    }

#define PV_WRITE_B(BUF)                                                         \
    {                                                                           \
        int* dst = (int*)(void*)&smB[BUF][(bhc * 4) * 40 + bi * 2];             \
        _Pragma("unroll") for (int j = 0; j < 4; ++j) {                         \
            __hip_bfloat16 h0 = __float2bfloat16(((const float*)&r0)[j]);       \
            __hip_bfloat16 h1 = __float2bfloat16(((const float*)&r1)[j]);       \
            dst[j * 20] = (int)*(unsigned short*)&h0 |                          \
                          ((int)*(unsigned short*)&h1 << 16);                   \
        }                                                                       \
    }

    PV_ISSUE_A(0, 0)
    PV_ISSUE_A(1, 1)
    PV_LOAD_B(0)
    PV_WRITE_B(0)          // compiler auto-waits on B(0) regs
    PV_LOAD_B(1)
    __builtin_amdgcn_sched_barrier(0);
    asm volatile("s_waitcnt vmcnt(4)" ::: "memory");   // A(0) landed
    asm volatile("s_waitcnt lgkmcnt(0)" ::: "memory"); // B(0) LDS visible
    __builtin_amdgcn_s_barrier();
    __builtin_amdgcn_sched_barrier(0);

#pragma unroll
    for (int k = 0; k < 16; ++k) {
        if (k + 2 < 16) PV_ISSUE_A(k + 2, (k + 2) % 3)
        {
            const short* At = &smA[k % 3][0];
            const short* Bt = &smB[k % 2][0];
            bf16x8 bfv[4];
#pragma unroll
            for (int n = 0; n < 4; ++n) {
                const int h = wn * 64 + n * 16 + fr;
                bfv[n] = *(const bf16x8*)(const void*)(Bt + h * 40 + quad * 8);
            }
            __builtin_amdgcn_s_setprio(1);     // T5
#pragma unroll
            for (int m = 0; m < 4; ++m) {
                const int row = wm * 64 + m * 16 + fr;
                const int slot = row * 4 + (quad ^ ((row >> 1) & 3));
                const bf16x8 af = *(const bf16x8*)(const void*)(At + slot * 8);
#pragma unroll
                for (int n = 0; n < 4; ++n)
                    acc[m][n] = __builtin_amdgcn_mfma_f32_16x16x32_bf16(
                        af, bfv[n], acc[m][n], 0, 0, 0);
            }
            __builtin_amdgcn_s_setprio(0);
        }
        if (k + 1 < 16) PV_WRITE_B((k + 1) % 2)   // auto-waits on B(k+1) regs
        if (k + 2 < 16) PV_LOAD_B(k + 2)
        __builtin_amdgcn_sched_barrier(0);
        if (k + 2 < 16) {
            asm volatile("s_waitcnt vmcnt(4)" ::: "memory");
        } else if (k + 1 < 16) {
            asm volatile("s_waitcnt vmcnt(0)" ::: "memory");
        }
        if (k + 1 < 16) {
            asm volatile("s_waitcnt lgkmcnt(0)" ::: "memory");
            __builtin_amdgcn_s_barrier();
            __builtin_amdgcn_sched_barrier(0);
        }
    }
#undef PV_ISSUE_A
#undef PV_LOAD_B
#undef PV_WRITE_B

    const long rowBase = (long)bz * 512 + by * 256 + wm * 64;
    const int colBase = bx * 128 + wn * 64;
#pragma unroll
    for (int m = 0; m < 4; ++m) {
#pragma unroll
        for (int n = 0; n < 4; ++n) {
            const int col = colBase + n * 16 + fr;
#pragma unroll
            for (int j = 0; j < 4; ++j) {
                const long row = rowBase + m * 16 + quad * 4 + j;
                Z[row * 1024 + col] = acc[m][n][j];
            }
        }
    }
}

// naive small transpose+convert: in [R][C] f32 -> out [C][R] bf16
__global__ __launch_bounds__(256) void transpose_cvt_kernel(const float* __restrict__ in,
                                                            __hip_bfloat16* __restrict__ out,
                                                            int R, int C) {
    const int o = blockIdx.x * 256 + threadIdx.x;
    if (o >= R * C) return;
    const int c = o / R;
    const int r = o - c * R;
    out[o] = __float2bfloat16(in[(long)r * C + c]);
}

extern "C" void kernel_launch(void* const* d_in, const int* in_sizes, int n_in,
                              void* d_out, int out_size, void* d_ws, size_t ws_size,
                              hipStream_t stream) {
    const float* X = (const float*)d_in[0];
    const int* sen = (const int*)d_in[1];
    const float* W = (const float*)d_in[2];
    const float* bias = (const float*)d_in[3];
    const float* U = (const float*)d_in[4];
    float* out = (float*)d_out;

    const int B = 64, T = 512, H = 1024, A = 256;
    const long M = (long)B * T;  // 32768

    // workspace: P (32Mi) | Wt (0.5Mi) | Ut (0.25Mi)
    char* ws = (char*)d_ws;
    __hip_bfloat16* Pbf = (__hip_bfloat16*)ws;
    __hip_bfloat16* Wt = (__hip_bfloat16*)(ws + M * T * 2);
    __hip_bfloat16* Ut = (__hip_bfloat16*)((char*)Wt + (long)H * A * 2);

    // 1. W^T [A][H], U^T [T][A]
    transpose_cvt_kernel<<<(H * A) / 256, 256, 0, stream>>>(W, Wt, H, A);
    transpose_cvt_kernel<<<(A * T) / 256, 256, 0, stream>>>(U, Ut, A, T);
    // 2+3. P = softmax(mask(tanh(X*W+b) * Ut^T)) — fused, alpha stays in LDS
    xw_sm_kernel<<<(int)(M / 64), 512, 0, stream>>>(X, Wt, Ut, bias, sen, Pbf);
    // 4. Z = P * X — r17 structure (group swizzle + counted vmcnt + T5)
    gemm_pv_kernel<<<dim3(H / 128, T / 256, B), 512, 0, stream>>>(Pbf, X, out);
}

// Round 19
// 135.187 us; speedup vs baseline: 1.1591x; 1.1591x over previous
//
#include <hip/hip_runtime.h>
#include <hip/hip_bf16.h>

typedef short short8 __attribute__((ext_vector_type(8)));
typedef short short4v __attribute__((ext_vector_type(4)));
typedef float f32x4 __attribute__((ext_vector_type(4)));
typedef __bf16 bf16x8 __attribute__((ext_vector_type(8)));

// ---- stage a ROWSx64 bf16 tile via global_load_lds, 16B-chunk XOR swizzle --
template <int ROWS>
__device__ __forceinline__ void stage2(const __hip_bfloat16* __restrict__ g,
                                       int ld, short* lds, int t) {
    const int w = t >> 6;
    const int lane = t & 63;
#pragma unroll
    for (int i = 0; i < ROWS / 64; ++i) {
        const int cb = i * 512 + w * 64;     // wave-uniform chunk base
        const int c = cb + lane;
        const int row = c >> 3;
        const int kc = (c & 7) ^ (row & 7);
        __builtin_amdgcn_global_load_lds((const void*)(g + (long)row * ld + kc * 8),
                                         (void*)(lds + cb * 8), 16, 0, 0);
    }
}

// -------- gemm_xw (r16 + T5 setprio): alpha = tanh(X*Wt^T + b) --------------
__global__ __launch_bounds__(512, 4) void gemm_xw_kernel(
    const float* __restrict__ Xf,           // [32768][1024]
    const __hip_bfloat16* __restrict__ Wt,  // [256][1024]
    __hip_bfloat16* __restrict__ alpha,     // [32768][256]
    const float* __restrict__ bias) {
    __shared__ __align__(16) short smB[3][8192];   // 16KB x3 (Wt tiles)
    __shared__ __align__(16) short smA[2][8192];   // 16KB x2 (X tiles, bf16)

    int bx, by;
    {   // group swizzle: both bx of a row-group on one XCD (r16-verified)
        const int lin = blockIdx.x + 2 * blockIdx.y;  // [0,512)
        const int xcd = lin & 7;
        const int idx = lin >> 3;                     // [0,64)
        by = xcd * 32 + (idx >> 1);                   // [0,256)
        bx = idx & 1;
    }

    const int t = threadIdx.x;
    const int w = t >> 6, lane = t & 63;
    const int wm = w >> 1, wn = w & 1;   // 4 x 2 waves
    const int fr = lane & 15, quad = lane >> 4;

    const float* Ab = Xf + (long)by * 128 * 1024;
    const __hip_bfloat16* Bb = Wt + (long)bx * 128 * 1024;

    int acs[2], arow[2], akc[2];
#pragma unroll
    for (int i = 0; i < 2; ++i) {
        acs[i] = i * 512 + t;
        arow[i] = acs[i] >> 3;
        akc[i] = ((acs[i] & 7) ^ (arow[i] & 7)) * 8;
    }

    f32x4 acc[2][4] = {};
    float4 rA[2][2];

#define XW_ISSUE_B(KT, BUF) stage2<128>(Bb + (KT) * 64, 1024, &smB[BUF][0], t);

#define XW_LOAD_A(KT)                                                           \
    _Pragma("unroll") for (int i = 0; i < 2; ++i) {                             \
        const float* src = Ab + (long)arow[i] * 1024 + (KT) * 64 + akc[i];      \
        rA[i][0] = *(const float4*)(src);                                       \
        rA[i][1] = *(const float4*)(src + 4);                                   \
    }

#define XW_WRITE_A(BUF)                                                         \
    _Pragma("unroll") for (int i = 0; i < 2; ++i) {                             \
        __hip_bfloat16 tmp[8] __attribute__((aligned(16)));                     \
        tmp[0] = __float2bfloat16(rA[i][0].x);                                  \
        tmp[1] = __float2bfloat16(rA[i][0].y);                                  \
        tmp[2] = __float2bfloat16(rA[i][0].z);                                  \
        tmp[3] = __float2bfloat16(rA[i][0].w);                                  \
        tmp[4] = __float2bfloat16(rA[i][1].x);                                  \
        tmp[5] = __float2bfloat16(rA[i][1].y);                                  \
        tmp[6] = __float2bfloat16(rA[i][1].z);                                  \
        tmp[7] = __float2bfloat16(rA[i][1].w);                                  \
        *(short8*)(void*)&smA[BUF][acs[i] * 8] = *(short8*)(void*)tmp;          \
    }

    XW_ISSUE_B(0, 0)
    XW_ISSUE_B(1, 1)
    XW_LOAD_A(0)
    XW_WRITE_A(0)          // auto-waits on A(0) regs
    XW_LOAD_A(1)
    __builtin_amdgcn_sched_barrier(0);
    asm volatile("s_waitcnt vmcnt(4)" ::: "memory");
    asm volatile("s_waitcnt lgkmcnt(0)" ::: "memory");
    __builtin_amdgcn_s_barrier();
    __builtin_amdgcn_sched_barrier(0);

#pragma unroll
    for (int k = 0; k < 16; ++k) {
        if (k + 2 < 16) XW_ISSUE_B(k + 2, (k + 2) % 3)
        {
            const short* At = &smA[k % 2][0];
            const short* Bt = &smB[k % 3][0];
            __builtin_amdgcn_s_setprio(1);     // T5: favor MFMA-phase wave
#pragma unroll
            for (int ks = 0; ks < 2; ++ks) {
                bf16x8 af[2], bfv[4];
                const int kc = ks * 4 + quad;
#pragma unroll
                for (int m = 0; m < 2; ++m) {
                    const int row = wm * 32 + m * 16 + fr;
                    const int chunk = row * 8 + (kc ^ (row & 7));
                    af[m] = *(const bf16x8*)(const void*)(At + chunk * 8);
                }
#pragma unroll
                for (int n = 0; n < 4; ++n) {
                    const int row = wn * 64 + n * 16 + fr;
                    const int chunk = row * 8 + (kc ^ (row & 7));
                    bfv[n] = *(const bf16x8*)(const void*)(Bt + chunk * 8);
                }
#pragma unroll
                for (int m = 0; m < 2; ++m)
#pragma unroll
                    for (int n = 0; n < 4; ++n)
                        acc[m][n] = __builtin_amdgcn_mfma_f32_16x16x32_bf16(
                            af[m], bfv[n], acc[m][n], 0, 0, 0);
            }
            __builtin_amdgcn_s_setprio(0);
        }
        if (k + 1 < 16) XW_WRITE_A((k + 1) % 2)   // auto-waits on A(k+1) regs
        if (k + 2 < 16) XW_LOAD_A(k + 2)
        __builtin_amdgcn_sched_barrier(0);
        if (k + 2 < 16) {
            asm volatile("s_waitcnt vmcnt(6)" ::: "memory");
        } else if (k + 1 < 16) {
            asm volatile("s_waitcnt vmcnt(0)" ::: "memory");
        }
        if (k + 1 < 16) {
            asm volatile("s_waitcnt lgkmcnt(0)" ::: "memory");
            __builtin_amdgcn_s_barrier();
            __builtin_amdgcn_sched_barrier(0);
        }
    }
#undef XW_ISSUE_B
#undef XW_LOAD_A
#undef XW_WRITE_A

    const long rowBase = (long)by * 128 + wm * 32;
    const int colBase = bx * 128 + wn * 64;
#pragma unroll
    for (int m = 0; m < 2; ++m) {
#pragma unroll
        for (int n = 0; n < 4; ++n) {
            const int col = colBase + n * 16 + fr;
            const float bv = bias[col];
#pragma unroll
            for (int j = 0; j < 4; ++j) {
                const long row = rowBase + m * 16 + quad * 4 + j;
                alpha[row * 256 + col] = __float2bfloat16(tanhf(acc[m][n][j] + bv));
            }
        }
    }
}

// -------- gemm_pv v10 + T5 setprio ------------------------------------------
// Tile 256t x 128h x BK=32s. A (P bf16): glds slot-XOR, triple-buf;
// B (X f32): reg-staged transposed, double-buf LDS. Group swizzle (r16).
__global__ __launch_bounds__(512, 4) void gemm_pv_kernel(
    const __hip_bfloat16* __restrict__ P,  // [B*512][512]
    const float* __restrict__ Xf,          // [B*512][1024]
    float* __restrict__ Z) {               // [B*512][1024]
    __shared__ __align__(16) short smA[3][8192];   // 16KB x3
    __shared__ __align__(16) short smB[2][5120];   // 10KB x2

    int bx, by, bz;
    {
        const int lin = blockIdx.x + 8 * (blockIdx.y + 2 * blockIdx.z);  // [0,1024)
        const int xcd = lin & 7;
        const int idx = lin >> 3;                 // [0,128)
        const int grp = xcd * 16 + (idx >> 3);    // [0,128) = (by,bz) group
        bx = idx & 7;
        by = grp & 1;
        bz = grp >> 1;
    }

    const int t = threadIdx.x;
    const int w = t >> 6, lane = t & 63;
    const int wm = w >> 1, wn = w & 1;   // 4 x 2 waves
    const int fr = lane & 15, quad = lane >> 4;

    const __hip_bfloat16* Ab = P + ((long)bz * 512 + by * 256) * 512;
    const float* Bb = Xf + (long)bz * 512 * 1024 + bx * 128;

    int acb[2], arow[2], akc[2];
#pragma unroll
    for (int i = 0; i < 2; ++i) {
        acb[i] = i * 512 + w * 64;           // wave-uniform
        const int s = acb[i] + lane;
        arow[i] = s >> 2;
        akc[i] = ((s & 3) ^ ((arow[i] >> 1) & 3)) * 8;
    }
    const int bi = t & 15;
    const int bhc = t >> 4;   // 0..31

    f32x4 acc[4][4] = {};
    float4 r0, r1;

#define PV_ISSUE_A(KT, BUF)                                                     \
    _Pragma("unroll") for (int i = 0; i < 2; ++i)                               \
        __builtin_amdgcn_global_load_lds(                                       \
            (const void*)(Ab + (long)arow[i] * 512 + (KT) * 32 + akc[i]),       \
            (void*)(&smA[BUF][acb[i] * 8]), 16, 0, 0);

#define PV_LOAD_B(KT)                                                           \
    {                                                                           \
        const float* s0 = Bb + (long)((KT) * 32 + 2 * bi) * 1024 + bhc * 4;     \
        r0 = *(const float4*)(s0);                                              \
        r1 = *(const float4*)(s0 + 1024);                                       \
    }

#define PV_WRITE_B(BUF)                                                         \
    {                                                                           \
        int* dst = (int*)(void*)&smB[BUF][(bhc * 4) * 40 + bi * 2];             \
        _Pragma("unroll") for (int j = 0; j < 4; ++j) {                         \
            __hip_bfloat16 h0 = __float2bfloat16(((const float*)&r0)[j]);       \
            __hip_bfloat16 h1 = __float2bfloat16(((const float*)&r1)[j]);       \
            dst[j * 20] = (int)*(unsigned short*)&h0 |                          \
                          ((int)*(unsigned short*)&h1 << 16);                   \
        }                                                                       \
    }

    PV_ISSUE_A(0, 0)
    PV_ISSUE_A(1, 1)
    PV_LOAD_B(0)
    PV_WRITE_B(0)          // compiler auto-waits on B(0) regs
    PV_LOAD_B(1)
    __builtin_amdgcn_sched_barrier(0);
    asm volatile("s_waitcnt vmcnt(4)" ::: "memory");   // A(0) landed
    asm volatile("s_waitcnt lgkmcnt(0)" ::: "memory"); // B(0) LDS visible
    __builtin_amdgcn_s_barrier();
    __builtin_amdgcn_sched_barrier(0);

#pragma unroll
    for (int k = 0; k < 16; ++k) {
        if (k + 2 < 16) PV_ISSUE_A(k + 2, (k + 2) % 3)
        {
            const short* At = &smA[k % 3][0];
            const short* Bt = &smB[k % 2][0];
            bf16x8 bfv[4];
#pragma unroll
            for (int n = 0; n < 4; ++n) {
                const int h = wn * 64 + n * 16 + fr;
                bfv[n] = *(const bf16x8*)(const void*)(Bt + h * 40 + quad * 8);
            }
            __builtin_amdgcn_s_setprio(1);     // T5: favor MFMA-phase wave
#pragma unroll
            for (int m = 0; m < 4; ++m) {
                const int row = wm * 64 + m * 16 + fr;
                const int slot = row * 4 + (quad ^ ((row >> 1) & 3));
                const bf16x8 af = *(const bf16x8*)(const void*)(At + slot * 8);
#pragma unroll
                for (int n = 0; n < 4; ++n)
                    acc[m][n] = __builtin_amdgcn_mfma_f32_16x16x32_bf16(
                        af, bfv[n], acc[m][n], 0, 0, 0);
            }
            __builtin_amdgcn_s_setprio(0);
        }
        if (k + 1 < 16) PV_WRITE_B((k + 1) % 2)   // auto-waits on B(k+1) regs
        if (k + 2 < 16) PV_LOAD_B(k + 2)
        __builtin_amdgcn_sched_barrier(0);
        if (k + 2 < 16) {
            asm volatile("s_waitcnt vmcnt(4)" ::: "memory");
        } else if (k + 1 < 16) {
            asm volatile("s_waitcnt vmcnt(0)" ::: "memory");
        }
        if (k + 1 < 16) {
            asm volatile("s_waitcnt lgkmcnt(0)" ::: "memory");
            __builtin_amdgcn_s_barrier();
            __builtin_amdgcn_sched_barrier(0);
        }
    }
#undef PV_ISSUE_A
#undef PV_LOAD_B
#undef PV_WRITE_B

    const long rowBase = (long)bz * 512 + by * 256 + wm * 64;
    const int colBase = bx * 128 + wn * 64;
#pragma unroll
    for (int m = 0; m < 4; ++m) {
#pragma unroll
        for (int n = 0; n < 4; ++n) {
            const int col = colBase + n * 16 + fr;
#pragma unroll
            for (int j = 0; j < 4; ++j) {
                const long row = rowBase + m * 16 + quad * 4 + j;
                Z[row * 1024 + col] = acc[m][n][j];
            }
        }
    }
}

// naive small transpose+convert: in [R][C] f32 -> out [C][R] bf16
__global__ __launch_bounds__(256) void transpose_cvt_kernel(const float* __restrict__ in,
                                                            __hip_bfloat16* __restrict__ out,
                                                            int R, int C) {
    const int o = blockIdx.x * 256 + threadIdx.x;
    if (o >= R * C) return;
    const int c = o / R;
    const int r = o - c * R;
    out[o] = __float2bfloat16(in[(long)r * C + c]);
}

// -------- score_softmax v2: barrier-free K-loop (r12, unchanged) -----------
__global__ __launch_bounds__(512, 4) void score_softmax_kernel(
    const __hip_bfloat16* __restrict__ Aa,  // alpha [32768][256]
    const __hip_bfloat16* __restrict__ Ut,  // [512][256]
    __hip_bfloat16* __restrict__ P,         // [32768][512]
    const int* __restrict__ sen) {
    __shared__ __align__(16) short At[2048 * 8];   // 32KB
    __shared__ float red[2][64][9];

    const int t = threadIdx.x;
    const int w = t >> 6, lane = t & 63;
    const int fr = lane & 15, quad = lane >> 4;
    const long row0 = (long)blockIdx.x * 64;
    const __hip_bfloat16* Ab = Aa + row0 * 256;

#pragma unroll
    for (int i = 0; i < 4; ++i) {
        const int cb = i * 512 + w * 64;
        const int c = cb + lane;
        const int row = c >> 5;
        const int kc = (c & 31) ^ (row & 7);
        __builtin_amdgcn_global_load_lds(
            (const void*)(Ab + (long)row * 256 + kc * 8),
            (void*)(At + cb * 8), 16, 0, 0);
    }

    f32x4 acc[4][4] = {};
    bf16x8 bfvs[2][4];

#define SM_LOAD_B(KT, S)                                                        \
    _Pragma("unroll") for (int n = 0; n < 4; ++n)                               \
        bfvs[S][n] = *(const bf16x8*)(const void*)(                             \
            Ut + (w * 64 + n * 16 + fr) * 256 + (KT) * 32 + quad * 8);

    SM_LOAD_B(0, 0)
    SM_LOAD_B(1, 1)
    __builtin_amdgcn_sched_barrier(0);
    asm volatile("s_waitcnt vmcnt(8)" ::: "memory");
    __builtin_amdgcn_s_barrier();
    __builtin_amdgcn_sched_barrier(0);

#define SM_STEP(KT)                                                             \
    {                                                                           \
        bf16x8 af[4];                                                           \
        _Pragma("unroll") for (int m = 0; m < 4; ++m) {                         \
            const int row = m * 16 + fr;                                        \
            const int g = row * 32 + (((KT) * 4 + quad) ^ (row & 7));           \
            af[m] = *(const bf16x8*)(const void*)(At + g * 8);                  \
        }                                                                       \
        _Pragma("unroll") for (int m = 0; m < 4; ++m)                           \
            _Pragma("unroll") for (int n = 0; n < 4; ++n)                       \
                acc[m][n] = __builtin_amdgcn_mfma_f32_16x16x32_bf16(            \
                    af[m], bfvs[(KT) & 1][n], acc[m][n], 0, 0, 0);              \
        if ((KT) + 2 < 8) { SM_LOAD_B((KT) + 2, (KT) & 1) }                     \
    }

    SM_STEP(0) SM_STEP(1) SM_STEP(2) SM_STEP(3)
    SM_STEP(4) SM_STEP(5) SM_STEP(6) SM_STEP(7)
#undef SM_STEP
#undef SM_LOAD_B
    __syncthreads();

    const int L = sen[row0 >> 9];
    bool valid[4];
#pragma unroll
    for (int n = 0; n < 4; ++n) valid[n] = (w * 64 + n * 16 + fr) < L;

    float mx[4][4];
#pragma unroll
    for (int m = 0; m < 4; ++m)
#pragma unroll
        for (int j = 0; j < 4; ++j) {
            float v = -3.0e38f;
#pragma unroll
            for (int n = 0; n < 4; ++n)
                if (valid[n]) v = fmaxf(v, acc[m][n][j]);
#pragma unroll
            for (int off = 8; off >= 1; off >>= 1) v = fmaxf(v, __shfl_xor(v, off, 64));
            mx[m][j] = v;
        }
    if (fr == 0) {
#pragma unroll
        for (int m = 0; m < 4; ++m)
#pragma unroll
            for (int j = 0; j < 4; ++j) red[0][m * 16 + quad * 4 + j][w] = mx[m][j];
    }
    __syncthreads();
    float rmax[4][4];
#pragma unroll
    for (int m = 0; m < 4; ++m)
#pragma unroll
        for (int j = 0; j < 4; ++j) {
            const int row = m * 16 + quad * 4 + j;
            float v = red[0][row][0];
#pragma unroll
            for (int ww = 1; ww < 8; ++ww) v = fmaxf(v, red[0][row][ww]);
            rmax[m][j] = v;
        }

    float sum[4][4];
#pragma unroll
    for (int m = 0; m < 4; ++m)
#pragma unroll
        for (int j = 0; j < 4; ++j) {
            float s = 0.f;
#pragma unroll
            for (int n = 0; n < 4; ++n) {
                float e = valid[n] ? __expf(acc[m][n][j] - rmax[m][j]) : 0.f;
                acc[m][n][j] = e;
                s += e;
            }
#pragma unroll
            for (int off = 8; off >= 1; off >>= 1) s += __shfl_xor(s, off, 64);
            sum[m][j] = s;
        }
    if (fr == 0) {
#pragma unroll
        for (int m = 0; m < 4; ++m)
#pragma unroll
            for (int j = 0; j < 4; ++j) red[1][m * 16 + quad * 4 + j][w] = sum[m][j];
    }
    __syncthreads();
#pragma unroll
    for (int m = 0; m < 4; ++m)
#pragma unroll
        for (int j = 0; j < 4; ++j) {
            const int row = m * 16 + quad * 4 + j;
            float s = 0.f;
#pragma unroll
            for (int ww = 0; ww < 8; ++ww) s += red[1][row][ww];
            const float inv = 1.f / s;
#pragma unroll
            for (int n = 0; n < 4; ++n)
                P[(row0 + row) * 512 + w * 64 + n * 16 + fr] =
                    __float2bfloat16(acc[m][n][j] * inv);
        }
}

extern "C" void kernel_launch(void* const* d_in, const int* in_sizes, int n_in,
                              void* d_out, int out_size, void* d_ws, size_t ws_size,
                              hipStream_t stream) {
    const float* X = (const float*)d_in[0];
    const int* sen = (const int*)d_in[1];
    const float* W = (const float*)d_in[2];
    const float* bias = (const float*)d_in[3];
    const float* U = (const float*)d_in[4];
    float* out = (float*)d_out;

    const int B = 64, T = 512, H = 1024, A = 256;
    const long M = (long)B * T;  // 32768

    // workspace: P (32Mi) | Wt (0.5Mi) | Ut (0.25Mi)
    char* ws = (char*)d_ws;
    __hip_bfloat16* Pbf = (__hip_bfloat16*)ws;
    __hip_bfloat16* Wt = (__hip_bfloat16*)(ws + M * T * 2);
    __hip_bfloat16* Ut = (__hip_bfloat16*)((char*)Wt + (long)H * A * 2);

    // d_out scratch: alpha bf16 at [64Mi,80Mi) — consumed by score_softmax
    // before gemm_pv overwrites all of d_out with Z.
    __hip_bfloat16* alpha = (__hip_bfloat16*)((char*)d_out + M * H * 2);

    // 1. W^T [A][H], U^T [T][A]
    transpose_cvt_kernel<<<(H * A) / 256, 256, 0, stream>>>(W, Wt, H, A);
    transpose_cvt_kernel<<<(A * T) / 256, 256, 0, stream>>>(U, Ut, A, T);
    // 2. alpha = tanh(X*W + b) — r16 + T5 setprio
    gemm_xw_kernel<<<dim3(2, 256), 512, 0, stream>>>(X, Wt, alpha, bias);
    // 3. P = softmax(alpha * U^T, mask) — barrier-free K-loop
    score_softmax_kernel<<<(int)(M / 64), 512, 0, stream>>>(alpha, Ut, Pbf, sen);
    // 4. Z = P * X — r16 group-swizzle structure + T5 setprio
    gemm_pv_kernel<<<dim3(H / 128, T / 256, B), 512, 0, stream>>>(Pbf, X, out);
}